// Round 16
// baseline (1459.327 us; speedup 1.0000x reference)
//
#include <hip/hip_runtime.h>
#include <math.h>

// ---------------------------------------------------------------------------
// TransformerBlock: B=2, T=2048, K=1024, H=4 (each head gets FULL dim K).
// R16 = R15 + parity-staggered wave roles + 2x K-loop unroll. R15 post-mortem:
// de-lockstep helped (95.2->87.2us, MfmaUtil 31->35%) but LDS and MFMA pipes
// still ~serial (6140cy/K-tile vs 2483 MFMA + 2311 LDS floors): all 8 waves
// run identical barrier-synced schedules, so both waves/SIMD read-batch
// together and the MFMA pipe idles. R16: odd waves (wid&1) execute quadrants
// in mirrored order (Q11,Q10,Q01,Q00) with reordered frag reads -- within a
// barrier window the buffer is read-only so this is race-free -- giving the
// SIMD scheduler (and setprio, T5) read-phase/MFMA-phase diversity to
// arbitrate. NT is even at all call sites -> hand 2x unroll, compile-time
// buffer indices. Stage/barrier/vmcnt placement identical to R15 (verified).
// Algebra (R5/R6): MT_h = s^2 Wk_h Wq_h^T ; VT_h = Wu_h^T Wv_h^T ;
// t = x MT^T ; S = t x^T (causal) ; P = softmax ; vvT = VT x^T ;
// x1 = x + sum_h P_h vv_h + bu ; out = x1 + relu(x1 W1 + b1) W2 + b2.
// Workspace (MB, 188): [0,8) xb | [8,16) Wqc | [16,24) Wvc | [24,32) Wkc'
// | [32,40) WuTb | [40,56) Wcomb | [56,88) tb | [88,120) vT | [120,184) S
// | [184,186) W1T | [186,188) W2T.  Aliases: Pb=[40,72) after sv;
// x1f=[8,24), x1b=[24,32), h1=[32,40) after combine.
// ---------------------------------------------------------------------------

typedef __attribute__((ext_vector_type(8))) short short8;   // 8 bf16 (4 VGPRs)
typedef __attribute__((ext_vector_type(4))) float f32x4;

__device__ __forceinline__ unsigned short f2bf(float f) {
  union { float f; unsigned int u; } v; v.f = f;
  unsigned int r = (v.u + 0x7fffu + ((v.u >> 16) & 1u)) >> 16;
  return (unsigned short)r;
}
__device__ __forceinline__ float bf2f(unsigned short b) {
  union { unsigned int u; float f; } v; v.u = ((unsigned int)b) << 16;
  return v.f;
}

#define GL2LDS(g, l)                                                          \
  __builtin_amdgcn_global_load_lds(                                           \
      (__attribute__((address_space(1))) void*)(g),                           \
      (__attribute__((address_space(3))) void*)(l), 16, 0, 0)

// ===========================================================================
// 256x256 core, 1-barrier/K-tile, parity-staggered wave roles.
// C = A @ BT^T (bf16 out).  LDS: A [2 buf][2 half][128][64] at lds[0..32K),
// B same at lds[32K..64K).  Stored slot (16B units) = logical ^ (row&7).
// ===========================================================================
__device__ __forceinline__ void core256(
    const unsigned short* __restrict__ A, const unsigned short* __restrict__ BT,
    int m0, int n0, int kmax, int lda, int ldb, int ldc, long long coff,
    unsigned short* __restrict__ Cb, unsigned short* lds) {
  const int tid = threadIdx.x;          // 0..511
  const int lane = tid & 63;
  const int wid = tid >> 6;             // 0..7
  const int wm = wid >> 2;              // 0..1 (m-half of 256)
  const int wn = wid & 3;               // 0..3 (64-col strip)
  const int par = __builtin_amdgcn_readfirstlane(wid & 1);  // wave role

  unsigned short* Als = lds;
  unsigned short* Bls = lds + 32768;

  // staging: per lane fetches global (row base+wid*8+(lane>>3), swizzled col)
  const int srow = wid * 8 + (lane >> 3);              // 0..63
  const int scol = ((lane & 7) ^ (lane >> 3)) * 8;     // pre-swizzled source
  const unsigned short* ag = A + (long long)(m0 + srow) * lda + scol;
  const unsigned short* bg = BT + (long long)(n0 + srow) * ldb + scol;

  const int frow = lane & 15;
  const int lq = lane >> 4;
  const int fsw = frow & 7;             // read-side slot xor

  f32x4 acc[8][4];
#pragma unroll
  for (int i = 0; i < 8; ++i)
#pragma unroll
    for (int j = 0; j < 4; ++j) acc[i][j] = {0.f, 0.f, 0.f, 0.f};

  short8 afr[4][2];      // A frags: current qm, 4 m x 2 kh
  short8 bfrE[2][2];     // B frags qn=0
  short8 bfrO[2][2];     // B frags qn=1

  const int NT = kmax >> 6;             // 64-col K-tiles (even at all sites)

  auto stageA = [&](int t_, int h_) {   // half h_ (128 rows) of tile t_
    unsigned short* d = Als + (t_ & 1) * 16384 + h_ * 8192 + wid * 512;
    const unsigned short* g = ag + ((long long)h_ * 128) * lda + t_ * 64;
    GL2LDS(g, d);
    GL2LDS(g + (long long)64 * lda, d + 4096);
  };
  auto stageB = [&](int t_, int h_) {
    unsigned short* d = Bls + (t_ & 1) * 16384 + h_ * 8192 + wid * 512;
    const unsigned short* g = bg + ((long long)h_ * 128) * ldb + t_ * 64;
    GL2LDS(g, d);
    GL2LDS(g + (long long)64 * ldb, d + 4096);
  };

  // reads take compile-time buffer index; compiler inserts counted lgkm
  // waits at the MFMA uses (no manual lgkmcnt/sched_barrier)
#define RDA(BUF, QM)                                                          \
  _Pragma("unroll")                                                           \
  for (int m_ = 0; m_ < 4; ++m_)                                              \
    _Pragma("unroll")                                                         \
    for (int kh_ = 0; kh_ < 2; ++kh_)                                         \
      afr[m_][kh_] = *(const short8*)(Als + (BUF) * 16384 + wm * 8192 +       \
          ((QM) * 64 + m_ * 16 + frow) * 64 + ((kh_ * 4 + lq) ^ fsw) * 8);

#define RDB(BUF, QN, BFR)                                                     \
  _Pragma("unroll")                                                           \
  for (int n_ = 0; n_ < 2; ++n_)                                              \
    _Pragma("unroll")                                                         \
    for (int kh_ = 0; kh_ < 2; ++kh_)                                         \
      BFR[n_][kh_] = *(const short8*)(Bls + (BUF) * 16384 + (wn >> 1) * 8192 +\
          ((wn & 1) * 64 + (QN) * 32 + n_ * 16 + frow) * 64 +                 \
          ((kh_ * 4 + lq) ^ fsw) * 8);

#define QUAD(QM, QN, BFR)                                                     \
  do {                                                                        \
    __builtin_amdgcn_s_setprio(1);                                            \
    _Pragma("unroll")                                                         \
    for (int m_ = 0; m_ < 4; ++m_)                                            \
      _Pragma("unroll")                                                       \
      for (int n_ = 0; n_ < 2; ++n_)                                          \
        _Pragma("unroll")                                                     \
        for (int kh_ = 0; kh_ < 2; ++kh_)                                     \
          acc[(QM) * 4 + m_][(QN) * 2 + n_] =                                 \
              __builtin_amdgcn_mfma_f32_16x16x32_bf16(                        \
                  afr[m_][kh_], BFR[n_][kh_],                                 \
                  acc[(QM) * 4 + m_][(QN) * 2 + n_], 0, 0, 0);                \
    __builtin_amdgcn_s_setprio(0);                                            \
  } while (0)

  // prologue: stage tile 0 fully, publish, issue first-quadrant reads
  stageA(0, 0); stageA(0, 1); stageB(0, 0); stageB(0, 1);
  asm volatile("s_waitcnt vmcnt(0)" ::: "memory");
  __builtin_amdgcn_s_barrier();
  if (par == 0) { RDA(0, 0) RDB(0, 0, bfrE) }
  else          { RDA(0, 1) RDB(0, 1, bfrO) }

  const int NTP = NT >> 1;
  for (int i = 0; i < NTP; ++i) {
    const int t0 = i * 2;
    const bool pf2 = (i + 1 < NTP);
    // ==== window A: consume tile t0 (buf0), stage tile t0+1 (buf1) ====
    stageA(t0 + 1, 0); stageA(t0 + 1, 1);
    if (par == 0) {            // even: Q00 -> Q01 -> Q10 -> Q11
      QUAD(0, 0, bfrE);
      RDB(0, 1, bfrO)
      stageB(t0 + 1, 0); stageB(t0 + 1, 1);
      QUAD(0, 1, bfrO);
      RDA(0, 1)
      QUAD(1, 0, bfrE);
      QUAD(1, 1, bfrO);
    } else {                   // odd: Q11 -> Q10 -> Q01 -> Q00 (mirrored)
      QUAD(1, 1, bfrO);
      RDB(0, 0, bfrE)
      stageB(t0 + 1, 0); stageB(t0 + 1, 1);
      QUAD(1, 0, bfrE);
      RDA(0, 0)
      QUAD(0, 1, bfrO);
      QUAD(0, 0, bfrE);
    }
    asm volatile("s_waitcnt vmcnt(0)" ::: "memory");
    __builtin_amdgcn_s_barrier();    // publish buf1 + reuse-guard buf0
    if (par == 0) { RDA(1, 0) RDB(1, 0, bfrE) }
    else          { RDA(1, 1) RDB(1, 1, bfrO) }
    // ==== window B: consume tile t0+1 (buf1), stage tile t0+2 (buf0) ====
    if (pf2) { stageA(t0 + 2, 0); stageA(t0 + 2, 1); }
    if (par == 0) {
      QUAD(0, 0, bfrE);
      RDB(1, 1, bfrO)
      if (pf2) { stageB(t0 + 2, 0); stageB(t0 + 2, 1); }
      QUAD(0, 1, bfrO);
      RDA(1, 1)
      QUAD(1, 0, bfrE);
      QUAD(1, 1, bfrO);
    } else {
      QUAD(1, 1, bfrO);
      RDB(1, 0, bfrE)
      if (pf2) { stageB(t0 + 2, 0); stageB(t0 + 2, 1); }
      QUAD(1, 0, bfrE);
      RDA(1, 0)
      QUAD(0, 1, bfrO);
      QUAD(0, 0, bfrE);
    }
    asm volatile("s_waitcnt vmcnt(0)" ::: "memory");
    __builtin_amdgcn_s_barrier();    // publish buf0 + reuse-guard buf1
    if (pf2) {
      if (par == 0) { RDA(0, 0) RDB(0, 0, bfrE) }
      else          { RDA(0, 1) RDB(0, 1, bfrO) }
    }
  }
#undef RDA
#undef RDB
#undef QUAD

  // epilogue: C/D layout col=lane&15, row=(lane>>4)*4+r (m89-verified)
  const int ccol = lane & 15;
  const int crow = lq * 4;
#pragma unroll
  for (int mi = 0; mi < 8; ++mi) {
#pragma unroll
    for (int ni = 0; ni < 4; ++ni) {
      const int gc = n0 + wn * 64 + ni * 16 + ccol;
#pragma unroll
      for (int r = 0; r < 4; ++r) {
        const int gr = m0 + wm * 128 + mi * 16 + crow + r;
        Cb[coff + (long long)gr * ldc + gc] = f2bf(acc[mi][ni][r]);
      }
    }
  }
}

// --- 256^2 kernel wrappers -------------------------------------------------

// combine: z=bid&7 (zb=z>>2 zh=z&3): zb0: MT_h = Wkc_h Wqc_h^T ; zb1: VT_h.
__global__ __launch_bounds__(512, 2) void g256_cmb(
    const unsigned short* __restrict__ Wkc,
    const unsigned short* __restrict__ Wqc,
    unsigned short* __restrict__ Wcomb) {
  __shared__ unsigned short lds[65536];
  const long long Mi = 1024 * 1024;
  const int bid = blockIdx.x;
  const int z = bid & 7, zb = z >> 2, zh = z & 3;
  const int j = bid >> 3;              // 0..15
  const int m0 = (j & 3) * 256, n0 = (j >> 2) * 256;
  core256(Wkc + (long long)zb * 4 * Mi + zh * 1024,
          Wqc + (long long)zb * 4 * Mi + zh * 1024,
          m0, n0, 1024, 4096, 4096, 1024,
          (long long)zb * 4 * Mi + (long long)zh * Mi, Wcomb, lds);
}

// t-GEMM: tb[4096,4096] = xb @ MT^T. 256 blocks, XCD m-stripe.
__global__ __launch_bounds__(512, 2) void g256_t(
    const unsigned short* __restrict__ xb,
    const unsigned short* __restrict__ Wcomb,
    unsigned short* __restrict__ tb) {
  __shared__ unsigned short lds[65536];
  const int bid = blockIdx.x;
  const int xcd = bid & 7;
  const int j = bid >> 3;              // 0..31
  const int m0 = (xcd * 2 + (j & 1)) * 256;
  const int n0 = (j >> 1) * 256;
  core256(xb, Wcomb, m0, n0, 1024, 1024, 1024, 4096, 0, tb, lds);
}

// Merged scores (bid<288, compact triangular over 8x8 256-tiles) + vvT.
__global__ __launch_bounds__(512, 2) void g256_sv(
    const unsigned short* __restrict__ xb,
    const unsigned short* __restrict__ Wcomb,
    const unsigned short* __restrict__ tb,
    unsigned short* __restrict__ S, unsigned short* __restrict__ vT) {
  __shared__ unsigned short lds[65536];
  const long long TT = (long long)2048 * 2048;
  const int bid = blockIdx.x;
  if (bid < 288) {                     // scores, triangular
    const int z = bid & 7, zb = z >> 2, zh = z & 3;
    const int idx = bid >> 3;          // 0..35
    int m = (int)((sqrtf(8.0f * idx + 1.0f) - 1.0f) * 0.5f);
    while ((m + 1) * (m + 2) / 2 <= idx) ++m;
    while (m * (m + 1) / 2 > idx) --m;
    const int m0 = m * 256;
    const int n0 = (idx - m * (m + 1) / 2) * 256;
    core256(tb + (long long)zb * 2048 * 4096 + zh * 1024,
            xb + (long long)zb * 2048 * 1024,
            m0, n0, 1024, 4096, 1024, 2048,
            (long long)(zb * 4 + zh) * TT, S, lds);
  } else {                             // vvT, XCD m-stripe
    const int r = bid - 288;           // 0..255
    const int xcd = r & 7;
    const int j = r >> 3;              // 0..31
    const int m0 = (xcd * 2 + (j & 1)) * 256;   // 16 m-tiles over 4096
    const int rest = j >> 1;           // 0..15
    const int bb = rest >> 3;
    const int n0 = (rest & 7) * 256;
    core256(Wcomb + (size_t)4096 * 1024, xb + (long long)bb * 2048 * 1024,
            m0, n0, 1024, 1024, 1024, 2048, (long long)bb * 4096 * 2048,
            vT, lds);
  }
}

// PV: per (b,h): P_h @ vvT_h^T -> bf16 head partials. grid (8z, 8m, 4n).
// kmax = m0+256 (softmax zero-fills the diagonal rectangle to 256-multiple).
__global__ __launch_bounds__(512, 2) void g256_pv(
    const unsigned short* __restrict__ S, const unsigned short* __restrict__ vT,
    unsigned short* __restrict__ Pb) {
  __shared__ unsigned short lds[65536];
  const long long TT = (long long)2048 * 2048;
  const long long MN = (long long)4096 * 1024;
  const int z = blockIdx.x, zb = z >> 2, zh = z & 3;
  const int m0 = blockIdx.y * 256, n0 = blockIdx.z * 256;
  core256(S + (long long)(zb * 4 + zh) * TT,
          vT + (long long)zb * 4096 * 2048 + (long long)zh * 1024 * 2048,
          m0, n0, m0 + 256, 2048, 2048, 1024,
          (long long)zh * MN + (long long)zb * 2048 * 1024, Pb, lds);
}

// ===========================================================================
// 128x64-tile core (FFN): acc[4][2] += A[128,k] @ BT[64,k]^T.  From R12
// (verified): depth-1 pipeline, counted vmcnt(3), slot^=(row>>1)&3 swizzle.
// ===========================================================================
__device__ __forceinline__ void core64(
    f32x4 acc[4][2], const unsigned short* __restrict__ A, int lda,
    const unsigned short* __restrict__ BT, int ldb, int kmax,
    unsigned short* As, unsigned short* Bs) {
  const int tid = threadIdx.x;
  const int lane = tid & 63;
  const int wv = tid >> 6;
  const int wm = wv & 1;               // 2 m-halves of 64
  const int wn = wv >> 1;              // 2 n-halves of 32
  const int srow = tid >> 2;           // 0..63
  const int scol = (((tid & 3) ^ ((srow >> 1) & 3)) * 8);
  const unsigned short* ap0 = A + (long long)srow * lda + scol;
  const unsigned short* ap1 = ap0 + (long long)64 * lda;
  const unsigned short* bp0 = BT + (long long)srow * ldb + scol;
  unsigned short* lA = As + wv * 512;
  unsigned short* lB = Bs + wv * 512;
  const int frow = lane & 15;
  const int fqs = (((lane >> 4) ^ ((frow >> 1) & 3)) * 8);

  int rs = 0, rc = 0;

  auto stage = [&]() {                 // 3 global_load_lds, 12KB
    unsigned short* a = lA + rs * 4096;
    GL2LDS(ap0, a); GL2LDS(ap1, a + 2048);
    GL2LDS(bp0, lB + rs * 2048);
    ap0 += 32; ap1 += 32; bp0 += 32;
    rs ^= 1;
  };
  auto compute = [&]() {               // 6 ds_read_b128 + 8 MFMA
    const unsigned short* Ac = As + rc * 4096;
    const unsigned short* Bc = Bs + rc * 2048;
    short8 afr[4], bfr[2];
#pragma unroll
    for (int mi = 0; mi < 4; ++mi)
      afr[mi] = *(const short8*)(Ac + (wm * 64 + mi * 16 + frow) * 32 + fqs);
#pragma unroll
    for (int ni = 0; ni < 2; ++ni)
      bfr[ni] = *(const short8*)(Bc + (wn * 32 + ni * 16 + frow) * 32 + fqs);
    __builtin_amdgcn_s_setprio(1);
#pragma unroll
    for (int mi = 0; mi < 4; ++mi)
#pragma unroll
      for (int ni = 0; ni < 2; ++ni)
        acc[mi][ni] = __builtin_amdgcn_mfma_f32_16x16x32_bf16(
            afr[mi], bfr[ni], acc[mi][ni], 0, 0, 0);
    __builtin_amdgcn_s_setprio(0);
    rc ^= 1;
  };

  const int nsteps = kmax >> 5;
  stage();
  for (int i = 0; i + 1 < nsteps; ++i) {
    stage();
    asm volatile("s_waitcnt vmcnt(3)" ::: "memory");
    __builtin_amdgcn_s_barrier();
    __builtin_amdgcn_sched_barrier(0);
    compute();
    __builtin_amdgcn_sched_barrier(0);
    __builtin_amdgcn_s_barrier();
  }
  asm volatile("s_waitcnt vmcnt(0)" ::: "memory");
  __builtin_amdgcn_s_barrier();
  __builtin_amdgcn_sched_barrier(0);
  compute();
}

// FFN GEMM, 128x64 tiles, full K=1024, fused epilogue.
__global__ __launch_bounds__(256) void gemm_ffn(
    const unsigned short* __restrict__ A, const unsigned short* __restrict__ BT,
    const float* __restrict__ bias, const float* __restrict__ resid,
    int do_relu, float* __restrict__ Cf, unsigned short* __restrict__ Cb) {
  __shared__ unsigned short As[8192];
  __shared__ unsigned short Bs[4096];
  const int bid = blockIdx.x;
  const int xcd = bid & 7;
  const int j = bid >> 3;              // [0,64)
  const int m0 = (xcd * 4 + (j & 3)) * 128;   // 32 m-tiles
  const int n0 = (j >> 2) * 64;               // 16 n-tiles
  f32x4 acc[4][2];
#pragma unroll
  for (int i = 0; i < 4; ++i)
#pragma unroll
    for (int j2 = 0; j2 < 2; ++j2) acc[i][j2] = {0.f, 0.f, 0.f, 0.f};
  core64(acc, A + (long long)m0 * 1024, 1024, BT + (long long)n0 * 1024, 1024,
         1024, As, Bs);
  const int lane = threadIdx.x & 63;
  const int wv = threadIdx.x >> 6;
  const int wm = wv & 1, wn = wv >> 1;
  const int ccol = lane & 15, crow = (lane >> 4) * 4;
#pragma unroll
  for (int mi = 0; mi < 4; ++mi) {
#pragma unroll
    for (int ni = 0; ni < 2; ++ni) {
      const int gc = n0 + wn * 32 + ni * 16 + ccol;
#pragma unroll
      for (int r = 0; r < 4; ++r) {
        const int gr = m0 + wm * 64 + mi * 16 + crow + r;
        float v = acc[mi][ni][r] + bias[gc];
        if (resid) v += resid[(long long)gr * 1024 + gc];
        if (do_relu) v = fmaxf(v, 0.f);
        const long long ci = (long long)gr * 1024 + gc;
        if (Cf) Cf[ci] = v;
        if (Cb) Cb[ci] = f2bf(v);
      }
    }
  }
}

// Partial-sum reduce + epilogue over bf16 partials (head-sum only now).
__global__ __launch_bounds__(256) void reduce_epi(
    const unsigned short* __restrict__ Pb, int S, long long MN,
    const float* __restrict__ bias, const float* __restrict__ resid,
    int do_relu, float* __restrict__ Cf, unsigned short* __restrict__ Cb) {
  const long long i4 = ((long long)blockIdx.x * 256 + threadIdx.x) * 4;
  if (i4 >= MN) return;
  float4 s = {0.f, 0.f, 0.f, 0.f};
  for (int t = 0; t < S; ++t) {
    const ushort4 p = *(const ushort4*)(Pb + (long long)t * MN + i4);
    s.x += bf2f(p.x); s.y += bf2f(p.y); s.z += bf2f(p.z); s.w += bf2f(p.w);
  }
  if (bias) {
    const int c0 = (int)(i4 & 1023);
    s.x += bias[c0]; s.y += bias[c0 + 1]; s.z += bias[c0 + 2]; s.w += bias[c0 + 3];
  }
  if (resid) {
    const float4 rr = *(const float4*)(resid + i4);
    s.x += rr.x; s.y += rr.y; s.z += rr.z; s.w += rr.w;
  }
  if (do_relu) {
    s.x = fmaxf(s.x, 0.f); s.y = fmaxf(s.y, 0.f);
    s.z = fmaxf(s.z, 0.f); s.w = fmaxf(s.w, 0.f);
  }
  if (Cf) *(float4*)(Cf + i4) = s;
  if (Cb) {
    ushort4 o;
    o.x = f2bf(s.x); o.y = f2bf(s.y); o.z = f2bf(s.z); o.w = f2bf(s.w);
    *(ushort4*)(Cb + i4) = o;
  }
}

// Row-wise causal softmax, in-place on bf16 scores. grid=(T, B*H), block=256.
// Zero-fills each row to a 256-multiple (PV reads m0+256-wide rectangles).
__global__ __launch_bounds__(256) void softmax_causal(unsigned short* S, int T) {
  const int q = blockIdx.x;
  unsigned short* row = S + ((long long)blockIdx.y * T + q) * T;
  const int tid = threadIdx.x;
  const int lane = tid & 63;
  const int wv = tid >> 6;
  const int n = q + 1;
  const int nz = (n + 255) & ~255;     // load/store limit (256-rounded)
  const int base = tid * 8;
  short8 raw = {};
  if (base < nz) raw = *(const short8*)(row + base);
  float vals[8];
  float m = -__builtin_inff();
#pragma unroll
  for (int i = 0; i < 8; ++i) {
    vals[i] = (base + i < n) ? bf2f((unsigned short)raw[i]) : -__builtin_inff();
    m = fmaxf(m, vals[i]);
  }
#pragma unroll
  for (int o = 32; o; o >>= 1) m = fmaxf(m, __shfl_xor(m, o, 64));
  __shared__ float red[4];
  if (lane == 0) red[wv] = m;
  __syncthreads();
  m = fmaxf(fmaxf(red[0], red[1]), fmaxf(red[2], red[3]));
  __syncthreads();
  float s = 0.f, e[8];
#pragma unroll
  for (int i = 0; i < 8; ++i) {
    e[i] = (base + i < n) ? __expf(vals[i] - m) : 0.f;
    s += e[i];
  }
#pragma unroll
  for (int o = 32; o; o >>= 1) s += __shfl_xor(s, o, 64);
  if (lane == 0) red[wv] = s;
  __syncthreads();
  s = red[0] + red[1] + red[2] + red[3];
  const float inv = 1.f / s;
  if (base < nz) {
    short8 o8;
#pragma unroll
    for (int i = 0; i < 8; ++i) o8[i] = (short)f2bf(e[i] * inv);
    *(short8*)(row + base) = o8;
  }
}

// All prep in one launch. grid=(4096, 7), block=256.
__global__ __launch_bounds__(256) void prep_all(
    const float* __restrict__ x, const float* __restrict__ Wq,
    const float* __restrict__ Wk, const float* __restrict__ Wv,
    const float* __restrict__ Wu, const float* __restrict__ W1,
    const float* __restrict__ W2, unsigned short* __restrict__ xb,
    unsigned short* __restrict__ Wqc, unsigned short* __restrict__ Wkc,
    unsigned short* __restrict__ Wvc, unsigned short* __restrict__ WuTb,
    unsigned short* __restrict__ W1T, unsigned short* __restrict__ W2T,
    float s2) {
  const int z = blockIdx.y;
  if (z <= 3) {
    const float* src = (z == 0) ? x : (z == 1) ? Wq : (z == 2) ? Wk : Wv;
    unsigned short* dst = (z == 0) ? xb : (z == 1) ? Wqc : (z == 2) ? Wkc : Wvc;
    const float sc = (z == 2) ? s2 : 1.0f;
    const long long i4 = ((long long)blockIdx.x * 256 + threadIdx.x) * 4;
    const float4 v = *(const float4*)(src + i4);
    ushort4 u;
    u.x = f2bf(v.x * sc); u.y = f2bf(v.y * sc);
    u.z = f2bf(v.z * sc); u.w = f2bf(v.w * sc);
    *(ushort4*)(dst + i4) = u;
    return;
  }
  const int R = (z == 4) ? 4096 : 1024;
  const int by = blockIdx.x >> 5;      // r-tile
  if (by * 32 >= R) return;
  const float* W = (z == 4) ? Wu : (z == 5) ? W1 : W2;
  unsigned short* WT = (z == 4) ? WuTb : (z == 5) ? W1T : W2T;
  __shared__ float tile[32][33];
  const int c0 = (blockIdx.x & 31) * 32;  // over C=1024
  const int r0 = by * 32;
  const int tx = threadIdx.x & 31;
  const int ty = threadIdx.x >> 5;
#pragma unroll
  for (int j = 0; j < 32; j += 8)
    tile[ty + j][tx] = W[(long long)(r0 + ty + j) * 1024 + c0 + tx];
  __syncthreads();
#pragma unroll
  for (int j = 0; j < 32; j += 8)
    WT[(long long)(c0 + ty + j) * R + r0 + tx] = f2bf(tile[tx][ty + j]);
}

extern "C" void kernel_launch(void* const* d_in, const int* in_sizes, int n_in,
                              void* d_out, int out_size, void* d_ws,
                              size_t ws_size, hipStream_t stream) {
  (void)in_sizes; (void)n_in; (void)out_size; (void)ws_size;
  const float* x  = (const float*)d_in[0];
  const float* Wq = (const float*)d_in[1];
  const float* Wk = (const float*)d_in[2];
  const float* Wv = (const float*)d_in[3];
  const float* Wu = (const float*)d_in[4];
  const float* bu = (const float*)d_in[5];
  const float* W1 = (const float*)d_in[6];
  const float* b1 = (const float*)d_in[7];
  const float* W2 = (const float*)d_in[8];
  const float* b2 = (const float*)d_in[9];
  float* out = (float*)d_out;

  const int T = 2048;
  const size_t MB = 1024 * 1024;
  const long long MN = (long long)4096 * 1024;  // 4 Mi elements

  char* w = (char*)d_ws;
  unsigned short* xb    = (unsigned short*)(w + 0 * MB);    //  8 MB
  unsigned short* Wqc   = (unsigned short*)(w + 8 * MB);    //  8 MB (dies)
  unsigned short* Wvc   = (unsigned short*)(w + 16 * MB);   //  8 MB (dies)
  unsigned short* Wkc   = (unsigned short*)(w + 24 * MB);   //  8 MB pre-scaled
  unsigned short* WuTb  = (unsigned short*)(w + 32 * MB);   //  8 MB (dies)
  unsigned short* Wcomb = (unsigned short*)(w + 40 * MB);   // 16 MB (dies)
  unsigned short* tb    = (unsigned short*)(w + 56 * MB);   // 32 MB (dies)
  unsigned short* vT    = (unsigned short*)(w + 88 * MB);   // 32 MB (dies)
  unsigned short* S     = (unsigned short*)(w + 120 * MB);  // 64 MB
  unsigned short* W1T   = (unsigned short*)(w + 184 * MB);  //  2 MB
  unsigned short* W2T   = (unsigned short*)(w + 186 * MB);  //  2 MB
  // liveness aliases:
  unsigned short* Pb    = (unsigned short*)(w + 40 * MB);   // 32 MB PV partials
  float*          x1f   = (float*)(w + 8 * MB);             // 16 MB
  unsigned short* x1b   = (unsigned short*)(w + 24 * MB);   //  8 MB
  unsigned short* h1    = (unsigned short*)(w + 32 * MB);   //  8 MB
  (void)WuTb; (void)Wvc;

  const float s2 = 0.03125f;  // (1024^-0.25)^2 = 2^-5

  // --- prep (all casts + transposes, one launch) ---
  prep_all<<<dim3(4096, 7), 256, 0, stream>>>(
      x, Wq, Wk, Wv, Wu, W1, W2, xb, Wqc, Wkc, Wvc, WuTb, W1T, W2T, s2);

  // --- merged combine (z=8): zb=0: MT_h; zb=1: VT_h -> Wcomb ---
  g256_cmb<<<dim3(128), 512, 0, stream>>>(Wkc, Wqc, Wcomb);

  // --- t = x @ MT^T ---
  g256_t<<<dim3(256), 512, 0, stream>>>(xb, Wcomb, tb);

  // --- scores (triangular, 288) + vvT (256) in one 544-block launch ---
  g256_sv<<<dim3(544), 512, 0, stream>>>(xb, Wcomb, tb, S, vT);

  softmax_causal<<<dim3(T, 8), 256, 0, stream>>>(S, T);

  // --- PV: per (b,h): P_h @ vvT_h^T -> bf16 head partials ---
  g256_pv<<<dim3(8, 8, 4), 512, 0, stream>>>(S, vT, Pb);

  // --- head-sum + bu + x residual -> x1 ---
  reduce_epi<<<dim3(4096), 256, 0, stream>>>(Pb, 4, MN, bu, x, 0, x1f, x1b);

  // --- FFN1: full-K 128x64 tiles, bias+relu fused -> h1 ---
  gemm_ffn<<<dim3(512), 256, 0, stream>>>(x1b, W1T, b1, nullptr, 1,
                                          nullptr, h1);

  // --- FFN2: full-K 128x64 tiles, + b2 + x1 residual -> out ---
  gemm_ffn<<<dim3(512), 256, 0, stream>>>(h1, W2T, b2, x1f, 0, out, nullptr);
}

// Round 20
// 390.722 us; speedup vs baseline: 3.7349x; 3.7349x over previous
//
#include <hip/hip_runtime.h>
#include <math.h>

// ---------------------------------------------------------------------------
// TransformerBlock: B=2, T=2048, K=1024, H=4 (each head gets FULL dim K).
// R17 = revert to R15 (verified 416.8us; sv 87.2us @ MfmaUtil 34.8%).
// R16 post-mortem: parity-staggered wave roles duplicated the K-loop body
// per parity -> register allocator spilled acc[8][4] to scratch (FETCH
// 76MB->656MB = scratch traffic, MfmaUtil 5.6%, 517us). Stagger theory
// untested; implementation path (branch duplication) is not viable with
// 128 accumulator regs. R15 core: 1 barrier + 1 vmcnt(0) per K-tile,
// compiler-scheduled counted lgkm waits, next-tile quad(0,0) reads issued
// right after boundary barrier, stages at iter top.
// Algebra (R5/R6): MT_h = s^2 Wk_h Wq_h^T ; VT_h = Wu_h^T Wv_h^T ;
// t = x MT^T ; S = t x^T (causal) ; P = softmax ; vvT = VT x^T ;
// x1 = x + sum_h P_h vv_h + bu ; out = x1 + relu(x1 W1 + b1) W2 + b2.
// Workspace (MB, 188): [0,8) xb | [8,16) Wqc | [16,24) Wvc | [24,32) Wkc'
// | [32,40) WuTb | [40,56) Wcomb | [56,88) tb | [88,120) vT | [120,184) S
// | [184,186) W1T | [186,188) W2T.  Aliases: Pb=[40,72) after sv;
// x1f=[8,24), x1b=[24,32), h1=[32,40) after combine.
// ---------------------------------------------------------------------------

typedef __attribute__((ext_vector_type(8))) short short8;   // 8 bf16 (4 VGPRs)
typedef __attribute__((ext_vector_type(4))) float f32x4;

__device__ __forceinline__ unsigned short f2bf(float f) {
  union { float f; unsigned int u; } v; v.f = f;
  unsigned int r = (v.u + 0x7fffu + ((v.u >> 16) & 1u)) >> 16;
  return (unsigned short)r;
}
__device__ __forceinline__ float bf2f(unsigned short b) {
  union { unsigned int u; float f; } v; v.u = ((unsigned int)b) << 16;
  return v.f;
}

#define GL2LDS(g, l)                                                          \
  __builtin_amdgcn_global_load_lds(                                           \
      (__attribute__((address_space(1))) void*)(g),                           \
      (__attribute__((address_space(3))) void*)(l), 16, 0, 0)

// ===========================================================================
// 256x256 core, 1-barrier/K-tile pipelined.  C = A @ BT^T (bf16 out).
// LDS layout (elements): A: [2 buf][2 half][128 row][64 col] at lds[0..32K),
// B same at lds[32K..64K).  Stored slot (16B units) = logical ^ (row&7).
// ===========================================================================
__device__ __forceinline__ void core256(
    const unsigned short* __restrict__ A, const unsigned short* __restrict__ BT,
    int m0, int n0, int kmax, int lda, int ldb, int ldc, long long coff,
    unsigned short* __restrict__ Cb, unsigned short* lds) {
  const int tid = threadIdx.x;          // 0..511
  const int lane = tid & 63;
  const int wid = tid >> 6;             // 0..7
  const int wm = wid >> 2;              // 0..1 (m-half of 256)
  const int wn = wid & 3;               // 0..3 (64-col strip)

  unsigned short* Als = lds;
  unsigned short* Bls = lds + 32768;

  // staging: per lane fetches global (row base+wid*8+(lane>>3), swizzled col)
  const int srow = wid * 8 + (lane >> 3);              // 0..63
  const int scol = ((lane & 7) ^ (lane >> 3)) * 8;     // pre-swizzled source
  const unsigned short* ag = A + (long long)(m0 + srow) * lda + scol;
  const unsigned short* bg = BT + (long long)(n0 + srow) * ldb + scol;

  const int frow = lane & 15;
  const int lq = lane >> 4;
  const int fsw = frow & 7;             // read-side slot xor

  f32x4 acc[8][4];
#pragma unroll
  for (int i = 0; i < 8; ++i)
#pragma unroll
    for (int j = 0; j < 4; ++j) acc[i][j] = {0.f, 0.f, 0.f, 0.f};

  short8 afr[4][2];      // A frags: current qm, 4 m x 2 kh
  short8 bfrE[2][2];     // B frags qn=0
  short8 bfrO[2][2];     // B frags qn=1

  const int NT = kmax >> 6;             // 64-col K-tiles

  auto stageA = [&](int t_, int h_) {   // half h_ (128 rows) of tile t_
    unsigned short* d = Als + (t_ & 1) * 16384 + h_ * 8192 + wid * 512;
    const unsigned short* g = ag + ((long long)h_ * 128) * lda + t_ * 64;
    GL2LDS(g, d);
    GL2LDS(g + (long long)64 * lda, d + 4096);
  };
  auto stageB = [&](int t_, int h_) {
    unsigned short* d = Bls + (t_ & 1) * 16384 + h_ * 8192 + wid * 512;
    const unsigned short* g = bg + ((long long)h_ * 128) * ldb + t_ * 64;
    GL2LDS(g, d);
    GL2LDS(g + (long long)64 * ldb, d + 4096);
  };

  // reads take explicit buffer index (compiler inserts counted lgkm waits
  // at the MFMA uses -- no manual lgkmcnt/sched_barrier)
#define RDA(BUF, QM)                                                          \
  _Pragma("unroll")                                                           \
  for (int m_ = 0; m_ < 4; ++m_)                                              \
    _Pragma("unroll")                                                         \
    for (int kh_ = 0; kh_ < 2; ++kh_)                                         \
      afr[m_][kh_] = *(const short8*)(Als + (BUF) * 16384 + wm * 8192 +       \
          ((QM) * 64 + m_ * 16 + frow) * 64 + ((kh_ * 4 + lq) ^ fsw) * 8);

#define RDB(BUF, QN, BFR)                                                     \
  _Pragma("unroll")                                                           \
  for (int n_ = 0; n_ < 2; ++n_)                                              \
    _Pragma("unroll")                                                         \
    for (int kh_ = 0; kh_ < 2; ++kh_)                                         \
      BFR[n_][kh_] = *(const short8*)(Bls + (BUF) * 16384 + (wn >> 1) * 8192 +\
          ((wn & 1) * 64 + (QN) * 32 + n_ * 16 + frow) * 64 +                 \
          ((kh_ * 4 + lq) ^ fsw) * 8);

#define QUAD(QM, QN, BFR)                                                     \
  do {                                                                        \
    __builtin_amdgcn_s_setprio(1);                                            \
    _Pragma("unroll")                                                         \
    for (int m_ = 0; m_ < 4; ++m_)                                            \
      _Pragma("unroll")                                                       \
      for (int n_ = 0; n_ < 2; ++n_)                                          \
        _Pragma("unroll")                                                     \
        for (int kh_ = 0; kh_ < 2; ++kh_)                                     \
          acc[(QM) * 4 + m_][(QN) * 2 + n_] =                                 \
              __builtin_amdgcn_mfma_f32_16x16x32_bf16(                        \
                  afr[m_][kh_], BFR[n_][kh_],                                 \
                  acc[(QM) * 4 + m_][(QN) * 2 + n_], 0, 0, 0);                \
    __builtin_amdgcn_s_setprio(0);                                            \
  } while (0)

  // prologue: stage tile 0 fully, publish, issue quad(0,0) reads
  stageA(0, 0); stageA(0, 1); stageB(0, 0); stageB(0, 1);
  asm volatile("s_waitcnt vmcnt(0)" ::: "memory");
  __builtin_amdgcn_s_barrier();
  RDA(0, 0)
  RDB(0, 0, bfrE)

  for (int t = 0; t < NT; ++t) {
    const int b = t & 1;
    const bool pf = (t + 1 < NT);
    // stage t+1's A into buf b^1 (reuse-guarded by the boundary barrier)
    if (pf) { stageA(t + 1, 0); stageA(t + 1, 1); }
    QUAD(0, 0, bfrE);                  // overlaps remaining quad(0,0) reads
    RDB(b, 1, bfrO)
    if (pf) { stageB(t + 1, 0); stageB(t + 1, 1); }
    QUAD(0, 1, bfrO);
    RDA(b, 1)                          // afr <- QM=1 rows of buf b
    QUAD(1, 0, bfrE);
    QUAD(1, 1, bfrO);
    // all 24 reads of buf b consumed above (implicit lgkm waits done).
    // tile t+1's 8 loads were issued ~a full iter ago -> drain is cheap.
    asm volatile("s_waitcnt vmcnt(0)" ::: "memory");
    __builtin_amdgcn_s_barrier();      // publish buf b^1 + reuse-guard buf b
    if (pf) {
      RDA(b ^ 1, 0)                    // next tile's quad(0,0) frags
      RDB(b ^ 1, 0, bfrE)
    }
  }
#undef RDA
#undef RDB
#undef QUAD

  // epilogue: C/D layout col=lane&15, row=(lane>>4)*4+r (m89-verified)
  const int ccol = lane & 15;
  const int crow = lq * 4;
#pragma unroll
  for (int mi = 0; mi < 8; ++mi) {
#pragma unroll
    for (int ni = 0; ni < 4; ++ni) {
      const int gc = n0 + wn * 64 + ni * 16 + ccol;
#pragma unroll
      for (int r = 0; r < 4; ++r) {
        const int gr = m0 + wm * 128 + mi * 16 + crow + r;
        Cb[coff + (long long)gr * ldc + gc] = f2bf(acc[mi][ni][r]);
      }
    }
  }
}

// --- 256^2 kernel wrappers -------------------------------------------------

// combine: z=bid&7 (zb=z>>2 zh=z&3): zb0: MT_h = Wkc_h Wqc_h^T ; zb1: VT_h.
__global__ __launch_bounds__(512, 2) void g256_cmb(
    const unsigned short* __restrict__ Wkc,
    const unsigned short* __restrict__ Wqc,
    unsigned short* __restrict__ Wcomb) {
  __shared__ unsigned short lds[65536];
  const long long Mi = 1024 * 1024;
  const int bid = blockIdx.x;
  const int z = bid & 7, zb = z >> 2, zh = z & 3;
  const int j = bid >> 3;              // 0..15
  const int m0 = (j & 3) * 256, n0 = (j >> 2) * 256;
  core256(Wkc + (long long)zb * 4 * Mi + zh * 1024,
          Wqc + (long long)zb * 4 * Mi + zh * 1024,
          m0, n0, 1024, 4096, 4096, 1024,
          (long long)zb * 4 * Mi + (long long)zh * Mi, Wcomb, lds);
}

// t-GEMM: tb[4096,4096] = xb @ MT^T. 256 blocks, XCD m-stripe.
__global__ __launch_bounds__(512, 2) void g256_t(
    const unsigned short* __restrict__ xb,
    const unsigned short* __restrict__ Wcomb,
    unsigned short* __restrict__ tb) {
  __shared__ unsigned short lds[65536];
  const int bid = blockIdx.x;
  const int xcd = bid & 7;
  const int j = bid >> 3;              // 0..31
  const int m0 = (xcd * 2 + (j & 1)) * 256;
  const int n0 = (j >> 1) * 256;
  core256(xb, Wcomb, m0, n0, 1024, 1024, 1024, 4096, 0, tb, lds);
}

// Merged scores (bid<288, compact triangular over 8x8 256-tiles) + vvT.
__global__ __launch_bounds__(512, 2) void g256_sv(
    const unsigned short* __restrict__ xb,
    const unsigned short* __restrict__ Wcomb,
    const unsigned short* __restrict__ tb,
    unsigned short* __restrict__ S, unsigned short* __restrict__ vT) {
  __shared__ unsigned short lds[65536];
  const long long TT = (long long)2048 * 2048;
  const int bid = blockIdx.x;
  if (bid < 288) {                     // scores, triangular
    const int z = bid & 7, zb = z >> 2, zh = z & 3;
    const int idx = bid >> 3;          // 0..35
    int m = (int)((sqrtf(8.0f * idx + 1.0f) - 1.0f) * 0.5f);
    while ((m + 1) * (m + 2) / 2 <= idx) ++m;
    while (m * (m + 1) / 2 > idx) --m;
    const int m0 = m * 256;
    const int n0 = (idx - m * (m + 1) / 2) * 256;
    core256(tb + (long long)zb * 2048 * 4096 + zh * 1024,
            xb + (long long)zb * 2048 * 1024,
            m0, n0, 1024, 4096, 1024, 2048,
            (long long)(zb * 4 + zh) * TT, S, lds);
  } else {                             // vvT, XCD m-stripe
    const int r = bid - 288;           // 0..255
    const int xcd = r & 7;
    const int j = r >> 3;              // 0..31
    const int m0 = (xcd * 2 + (j & 1)) * 256;   // 16 m-tiles over 4096
    const int rest = j >> 1;           // 0..15
    const int bb = rest >> 3;
    const int n0 = (rest & 7) * 256;
    core256(Wcomb + (size_t)4096 * 1024, xb + (long long)bb * 2048 * 1024,
            m0, n0, 1024, 1024, 1024, 2048, (long long)bb * 4096 * 2048,
            vT, lds);
  }
}

// PV: per (b,h): P_h @ vvT_h^T -> bf16 head partials. grid (8z, 8m, 4n).
// kmax = m0+256 (softmax zero-fills the diagonal rectangle to 256-multiple).
__global__ __launch_bounds__(512, 2) void g256_pv(
    const unsigned short* __restrict__ S, const unsigned short* __restrict__ vT,
    unsigned short* __restrict__ Pb) {
  __shared__ unsigned short lds[65536];
  const long long TT = (long long)2048 * 2048;
  const long long MN = (long long)4096 * 1024;
  const int z = blockIdx.x, zb = z >> 2, zh = z & 3;
  const int m0 = blockIdx.y * 256, n0 = blockIdx.z * 256;
  core256(S + (long long)(zb * 4 + zh) * TT,
          vT + (long long)zb * 4096 * 2048 + (long long)zh * 1024 * 2048,
          m0, n0, m0 + 256, 2048, 2048, 1024,
          (long long)zh * MN + (long long)zb * 2048 * 1024, Pb, lds);
}

// ===========================================================================
// 128x64-tile core (FFN): acc[4][2] += A[128,k] @ BT[64,k]^T.  From R12
// (verified): depth-1 pipeline, counted vmcnt(3), slot^=(row>>1)&3 swizzle.
// ===========================================================================
__device__ __forceinline__ void core64(
    f32x4 acc[4][2], const unsigned short* __restrict__ A, int lda,
    const unsigned short* __restrict__ BT, int ldb, int kmax,
    unsigned short* As, unsigned short* Bs) {
  const int tid = threadIdx.x;
  const int lane = tid & 63;
  const int wv = tid >> 6;
  const int wm = wv & 1;               // 2 m-halves of 64
  const int wn = wv >> 1;              // 2 n-halves of 32
  const int srow = tid >> 2;           // 0..63
  const int scol = (((tid & 3) ^ ((srow >> 1) & 3)) * 8);
  const unsigned short* ap0 = A + (long long)srow * lda + scol;
  const unsigned short* ap1 = ap0 + (long long)64 * lda;
  const unsigned short* bp0 = BT + (long long)srow * ldb + scol;
  unsigned short* lA = As + wv * 512;
  unsigned short* lB = Bs + wv * 512;
  const int frow = lane & 15;
  const int fqs = (((lane >> 4) ^ ((frow >> 1) & 3)) * 8);

  int rs = 0, rc = 0;

  auto stage = [&]() {                 // 3 global_load_lds, 12KB
    unsigned short* a = lA + rs * 4096;
    GL2LDS(ap0, a); GL2LDS(ap1, a + 2048);
    GL2LDS(bp0, lB + rs * 2048);
    ap0 += 32; ap1 += 32; bp0 += 32;
    rs ^= 1;
  };
  auto compute = [&]() {               // 6 ds_read_b128 + 8 MFMA
    const unsigned short* Ac = As + rc * 4096;
    const unsigned short* Bc = Bs + rc * 2048;
    short8 afr[4], bfr[2];
#pragma unroll
    for (int mi = 0; mi < 4; ++mi)
      afr[mi] = *(const short8*)(Ac + (wm * 64 + mi * 16 + frow) * 32 + fqs);
#pragma unroll
    for (int ni = 0; ni < 2; ++ni)
      bfr[ni] = *(const short8*)(Bc + (wn * 32 + ni * 16 + frow) * 32 + fqs);
    __builtin_amdgcn_s_setprio(1);
#pragma unroll
    for (int mi = 0; mi < 4; ++mi)
#pragma unroll
      for (int ni = 0; ni < 2; ++ni)
        acc[mi][ni] = __builtin_amdgcn_mfma_f32_16x16x32_bf16(
            afr[mi], bfr[ni], acc[mi][ni], 0, 0, 0);
    __builtin_amdgcn_s_setprio(0);
    rc ^= 1;
  };

  const int nsteps = kmax >> 5;
  stage();
  for (int i = 0; i + 1 < nsteps; ++i) {
    stage();
    asm volatile("s_waitcnt vmcnt(3)" ::: "memory");
    __builtin_amdgcn_s_barrier();
    __builtin_amdgcn_sched_barrier(0);
    compute();
    __builtin_amdgcn_sched_barrier(0);
    __builtin_amdgcn_s_barrier();
  }
  asm volatile("s_waitcnt vmcnt(0)" ::: "memory");
  __builtin_amdgcn_s_barrier();
  __builtin_amdgcn_sched_barrier(0);
  compute();
}

// FFN GEMM, 128x64 tiles, full K=1024, fused epilogue.
__global__ __launch_bounds__(256) void gemm_ffn(
    const unsigned short* __restrict__ A, const unsigned short* __restrict__ BT,
    const float* __restrict__ bias, const float* __restrict__ resid,
    int do_relu, float* __restrict__ Cf, unsigned short* __restrict__ Cb) {
  __shared__ unsigned short As[8192];
  __shared__ unsigned short Bs[4096];
  const int bid = blockIdx.x;
  const int xcd = bid & 7;
  const int j = bid >> 3;              // [0,64)
  const int m0 = (xcd * 4 + (j & 3)) * 128;   // 32 m-tiles
  const int n0 = (j >> 2) * 64;               // 16 n-tiles
  f32x4 acc[4][2];
#pragma unroll
  for (int i = 0; i < 4; ++i)
#pragma unroll
    for (int j2 = 0; j2 < 2; ++j2) acc[i][j2] = {0.f, 0.f, 0.f, 0.f};
  core64(acc, A + (long long)m0 * 1024, 1024, BT + (long long)n0 * 1024, 1024,
         1024, As, Bs);
  const int lane = threadIdx.x & 63;
  const int wv = threadIdx.x >> 6;
  const int wm = wv & 1, wn = wv >> 1;
  const int ccol = lane & 15, crow = (lane >> 4) * 4;
#pragma unroll
  for (int mi = 0; mi < 4; ++mi) {
#pragma unroll
    for (int ni = 0; ni < 2; ++ni) {
      const int gc = n0 + wn * 32 + ni * 16 + ccol;
#pragma unroll
      for (int r = 0; r < 4; ++r) {
        const int gr = m0 + wm * 64 + mi * 16 + crow + r;
        float v = acc[mi][ni][r] + bias[gc];
        if (resid) v += resid[(long long)gr * 1024 + gc];
        if (do_relu) v = fmaxf(v, 0.f);
        const long long ci = (long long)gr * 1024 + gc;
        if (Cf) Cf[ci] = v;
        if (Cb) Cb[ci] = f2bf(v);
      }
    }
  }
}

// Partial-sum reduce + epilogue over bf16 partials (head-sum only now).
__global__ __launch_bounds__(256) void reduce_epi(
    const unsigned short* __restrict__ Pb, int S, long long MN,
    const float* __restrict__ bias, const float* __restrict__ resid,
    int do_relu, float* __restrict__ Cf, unsigned short* __restrict__ Cb) {
  const long long i4 = ((long long)blockIdx.x * 256 + threadIdx.x) * 4;
  if (i4 >= MN) return;
  float4 s = {0.f, 0.f, 0.f, 0.f};
  for (int t = 0; t < S; ++t) {
    const ushort4 p = *(const ushort4*)(Pb + (long long)t * MN + i4);
    s.x += bf2f(p.x); s.y += bf2f(p.y); s.z += bf2f(p.z); s.w += bf2f(p.w);
  }
  if (bias) {
    const int c0 = (int)(i4 & 1023);
    s.x += bias[c0]; s.y += bias[c0 + 1]; s.z += bias[c0 + 2]; s.w += bias[c0 + 3];
  }
  if (resid) {
    const float4 rr = *(const float4*)(resid + i4);
    s.x += rr.x; s.y += rr.y; s.z += rr.z; s.w += rr.w;
  }
  if (do_relu) {
    s.x = fmaxf(s.x, 0.f); s.y = fmaxf(s.y, 0.f);
    s.z = fmaxf(s.z, 0.f); s.w = fmaxf(s.w, 0.f);
  }
  if (Cf) *(float4*)(Cf + i4) = s;
  if (Cb) {
    ushort4 o;
    o.x = f2bf(s.x); o.y = f2bf(s.y); o.z = f2bf(s.z); o.w = f2bf(s.w);
    *(ushort4*)(Cb + i4) = o;
  }
}

// Row-wise causal softmax, in-place on bf16 scores. grid=(T, B*H), block=256.
// Zero-fills each row to a 256-multiple (PV reads m0+256-wide rectangles).
__global__ __launch_bounds__(256) void softmax_causal(unsigned short* S, int T) {
  const int q = blockIdx.x;
  unsigned short* row = S + ((long long)blockIdx.y * T + q) * T;
  const int tid = threadIdx.x;
  const int lane = tid & 63;
  const int wv = tid >> 6;
  const int n = q + 1;
  const int nz = (n + 255) & ~255;     // load/store limit (256-rounded)
  const int base = tid * 8;
  short8 raw = {};
  if (base < nz) raw = *(const short8*)(row + base);
  float vals[8];
  float m = -__builtin_inff();
#pragma unroll
  for (int i = 0; i < 8; ++i) {
    vals[i] = (base + i < n) ? bf2f((unsigned short)raw[i]) : -__builtin_inff();
    m = fmaxf(m, vals[i]);
  }
#pragma unroll
  for (int o = 32; o; o >>= 1) m = fmaxf(m, __shfl_xor(m, o, 64));
  __shared__ float red[4];
  if (lane == 0) red[wv] = m;
  __syncthreads();
  m = fmaxf(fmaxf(red[0], red[1]), fmaxf(red[2], red[3]));
  __syncthreads();
  float s = 0.f, e[8];
#pragma unroll
  for (int i = 0; i < 8; ++i) {
    e[i] = (base + i < n) ? __expf(vals[i] - m) : 0.f;
    s += e[i];
  }
#pragma unroll
  for (int o = 32; o; o >>= 1) s += __shfl_xor(s, o, 64);
  if (lane == 0) red[wv] = s;
  __syncthreads();
  s = red[0] + red[1] + red[2] + red[3];
  const float inv = 1.f / s;
  if (base < nz) {
    short8 o8;
#pragma unroll
    for (int i = 0; i < 8; ++i) o8[i] = (short)f2bf(e[i] * inv);
    *(short8*)(row + base) = o8;
  }
}

// All prep in one launch. grid=(4096, 7), block=256.
__global__ __launch_bounds__(256) void prep_all(
    const float* __restrict__ x, const float* __restrict__ Wq,
    const float* __restrict__ Wk, const float* __restrict__ Wv,
    const float* __restrict__ Wu, const float* __restrict__ W1,
    const float* __restrict__ W2, unsigned short* __restrict__ xb,
    unsigned short* __restrict__ Wqc, unsigned short* __restrict__ Wkc,
    unsigned short* __restrict__ Wvc, unsigned short* __restrict__ WuTb,
    unsigned short* __restrict__ W1T, unsigned short* __restrict__ W2T,
    float s2) {
  const int z = blockIdx.y;
  if (z <= 3) {
    const float* src = (z == 0) ? x : (z == 1) ? Wq : (z == 2) ? Wk : Wv;
    unsigned short* dst = (z == 0) ? xb : (z == 1) ? Wqc : (z == 2) ? Wkc : Wvc;
    const float sc = (z == 2) ? s2 : 1.0f;
    const long long i4 = ((long long)blockIdx.x * 256 + threadIdx.x) * 4;
    const float4 v = *(const float4*)(src + i4);
    ushort4 u;
    u.x = f2bf(v.x * sc); u.y = f2bf(v.y * sc);
    u.z = f2bf(v.z * sc); u.w = f2bf(v.w * sc);
    *(ushort4*)(dst + i4) = u;
    return;
  }
  const int R = (z == 4) ? 4096 : 1024;
  const int by = blockIdx.x >> 5;      // r-tile
  if (by * 32 >= R) return;
  const float* W = (z == 4) ? Wu : (z == 5) ? W1 : W2;
  unsigned short* WT = (z == 4) ? WuTb : (z == 5) ? W1T : W2T;
  __shared__ float tile[32][33];
  const int c0 = (blockIdx.x & 31) * 32;  // over C=1024
  const int r0 = by * 32;
  const int tx = threadIdx.x & 31;
  const int ty = threadIdx.x >> 5;
#pragma unroll
  for (int j = 0; j < 32; j += 8)
    tile[ty + j][tx] = W[(long long)(r0 + ty + j) * 1024 + c0 + tx];
  __syncthreads();
#pragma unroll
  for (int j = 0; j < 32; j += 8)
    WT[(long long)(c0 + ty + j) * R + r0 + tx] = f2bf(tile[tx][ty + j]);
}

extern "C" void kernel_launch(void* const* d_in, const int* in_sizes, int n_in,
                              void* d_out, int out_size, void* d_ws,
                              size_t ws_size, hipStream_t stream) {
  (void)in_sizes; (void)n_in; (void)out_size; (void)ws_size;
  const float* x  = (const float*)d_in[0];
  const float* Wq = (const float*)d_in[1];
  const float* Wk = (const float*)d_in[2];
  const float* Wv = (const float*)d_in[3];
  const float* Wu = (const float*)d_in[4];
  const float* bu = (const float*)d_in[5];
  const float* W1 = (const float*)d_in[6];
  const float* b1 = (const float*)d_in[7];
  const float* W2 = (const float*)d_in[8];
  const float* b2 = (const float*)d_in[9];
  float* out = (float*)d_out;

  const int T = 2048;
  const size_t MB = 1024 * 1024;
  const long long MN = (long long)4096 * 1024;  // 4 Mi elements

  char* w = (char*)d_ws;
  unsigned short* xb    = (unsigned short*)(w + 0 * MB);    //  8 MB
  unsigned short* Wqc   = (unsigned short*)(w + 8 * MB);    //  8 MB (dies)
  unsigned short* Wvc   = (unsigned short*)(w + 16 * MB);   //  8 MB (dies)
  unsigned short* Wkc   = (unsigned short*)(w + 24 * MB);   //  8 MB pre-scaled
  unsigned short* WuTb  = (unsigned short*)(w + 32 * MB);   //  8 MB (dies)
  unsigned short* Wcomb = (unsigned short*)(w + 40 * MB);   // 16 MB (dies)
  unsigned short* tb    = (unsigned short*)(w + 56 * MB);   // 32 MB (dies)
  unsigned short* vT    = (unsigned short*)(w + 88 * MB);   // 32 MB (dies)
  unsigned short* S     = (unsigned short*)(w + 120 * MB);  // 64 MB
  unsigned short* W1T   = (unsigned short*)(w + 184 * MB);  //  2 MB
  unsigned short* W2T   = (unsigned short*)(w + 186 * MB);  //  2 MB
  // liveness aliases:
  unsigned short* Pb    = (unsigned short*)(w + 40 * MB);   // 32 MB PV partials
  float*          x1f   = (float*)(w + 8 * MB);             // 16 MB
  unsigned short* x1b   = (unsigned short*)(w + 24 * MB);   //  8 MB
  unsigned short* h1    = (unsigned short*)(w + 32 * MB);   //  8 MB
  (void)WuTb; (void)Wvc;

  const float s2 = 0.03125f;  // (1024^-0.25)^2 = 2^-5

  // --- prep (all casts + transposes, one launch) ---
  prep_all<<<dim3(4096, 7), 256, 0, stream>>>(
      x, Wq, Wk, Wv, Wu, W1, W2, xb, Wqc, Wkc, Wvc, WuTb, W1T, W2T, s2);

  // --- merged combine (z=8): zb=0: MT_h; zb=1: VT_h -> Wcomb ---
  g256_cmb<<<dim3(128), 512, 0, stream>>>(Wkc, Wqc, Wcomb);

  // --- t = x @ MT^T ---
  g256_t<<<dim3(256), 512, 0, stream>>>(xb, Wcomb, tb);

  // --- scores (triangular, 288) + vvT (256) in one 544-block launch ---
  g256_sv<<<dim3(544), 512, 0, stream>>>(xb, Wcomb, tb, S, vT);

  softmax_causal<<<dim3(T, 8), 256, 0, stream>>>(S, T);

  // --- PV: per (b,h): P_h @ vvT_h^T -> bf16 head partials ---
  g256_pv<<<dim3(8, 8, 4), 512, 0, stream>>>(S, vT, Pb);

  // --- head-sum + bu + x residual -> x1 ---
  reduce_epi<<<dim3(4096), 256, 0, stream>>>(Pb, 4, MN, bu, x, 0, x1f, x1b);

  // --- FFN1: full-K 128x64 tiles, bias+relu fused -> h1 ---
  gemm_ffn<<<dim3(512), 256, 0, stream>>>(x1b, W1T, b1, nullptr, 1,
                                          nullptr, h1);

  // --- FFN2: full-K 128x64 tiles, + b2 + x1 residual -> out ---
  gemm_ffn<<<dim3(512), 256, 0, stream>>>(h1, W2T, b2, x1f, 0, out, nullptr);
}